// Round 1
// baseline (202.159 us; speedup 1.0000x reference)
//
#include <hip/hip_runtime.h>
#include <math.h>

#define N_TOK 40
#define N1    41      // N_TOK + 1
#define BS    8
#define DD    256     // D
#define HH    256     // H
#define NEGV  (-1e30f)
#define NTRI  10660   // C(41,3)
#define NTASK (NTRI * BS)  // 85280
#define ROWF  (BS * N1 * HH)  // 83968 floats per [b][t][h] array

// ---------------- Kernel 1: projections P = enc@W1L, Qb = enc@W1R + b1, D = P - Q
__global__ __launch_bounds__(256) void k_proj(
    const float* __restrict__ enc, const float* __restrict__ W1,
    const float* __restrict__ b1,
    float* __restrict__ P, float* __restrict__ Qb, float* __restrict__ Dd)
{
    const int t = blockIdx.x;    // 0..40
    const int h = threadIdx.x;   // 0..255
    __shared__ float e[BS][DD];
    #pragma unroll
    for (int b = 0; b < BS; ++b)
        e[b][h] = enc[(t * BS + b) * DD + h];
    __syncthreads();

    float accP[BS], accQ[BS];
    #pragma unroll
    for (int b = 0; b < BS; ++b) { accP[b] = 0.f; accQ[b] = 0.f; }

    for (int d = 0; d < DD; ++d) {
        float wp = W1[d * HH + h];
        float wq = W1[(DD + d) * HH + h];
        #pragma unroll
        for (int b = 0; b < BS; ++b) {
            float ev = e[b][d];
            accP[b] = fmaf(ev, wp, accP[b]);
            accQ[b] = fmaf(ev, wq, accQ[b]);
        }
    }
    float bb = b1[h];
    #pragma unroll
    for (int b = 0; b < BS; ++b) {
        int idx = ((b * N1) + t) * HH + h;
        P[idx]  = accP[b];
        Qb[idx] = accQ[b] + bb;
        Dd[idx] = accP[b] - accQ[b];
    }
}

// ---------------- Kernel 2: per-triple scores SE[tri][b] = logsumexp_o(S0,S1)
__global__ __launch_bounds__(256) void k_score(
    const float* __restrict__ P, const float* __restrict__ Qb,
    const float* __restrict__ Dd, const float* __restrict__ W2,
    const float* __restrict__ b2, float* __restrict__ S)
{
    int tau = blockIdx.x * 256 + threadIdx.x;
    if (tau >= NTASK) return;
    // b-outer ordering: a wave shares b and walks consecutive triples -> P/Qb rows broadcast
    int b   = tau / NTRI;
    int tri = tau - b * NTRI;

    // decode tri -> (w, i, j') in (w,i,j') enumeration order
    int rem = tri, w = 2;
    while (true) {
        int cnt = (N1 - w) * (w - 1);
        if (rem < cnt) break;
        rem -= cnt; ++w;
    }
    int nj = w - 1;
    int i  = rem / nj;
    int jp = rem - i * nj;
    int j  = i + 1 + jp;
    int k  = i + w;

    const float4* Pr = (const float4*)(P  + ((b * N1 + i) << 8));
    const float4* Qr = (const float4*)(Qb + ((b * N1 + k) << 8));
    const float4* Dr = (const float4*)(Dd + ((b * N1 + j) << 8));

    float s0 = 0.f, s1 = 0.f;
    #pragma unroll 4
    for (int h4 = 0; h4 < HH / 4; ++h4) {
        float4 p = Pr[h4], q = Qr[h4], dd = Dr[h4];
        float r0 = fmaxf(dd.x + q.x - p.x, 0.f);
        float r1 = fmaxf(dd.y + q.y - p.y, 0.f);
        float r2 = fmaxf(dd.z + q.z - p.z, 0.f);
        float r3 = fmaxf(dd.w + q.w - p.w, 0.f);
        int hb = h4 * 8;  // W2 is [h][2] row-major; uniform index -> scalar loads
        s0 = fmaf(r0, W2[hb + 0], s0); s1 = fmaf(r0, W2[hb + 1], s1);
        s0 = fmaf(r1, W2[hb + 2], s0); s1 = fmaf(r1, W2[hb + 3], s1);
        s0 = fmaf(r2, W2[hb + 4], s0); s1 = fmaf(r2, W2[hb + 5], s1);
        s0 = fmaf(r3, W2[hb + 6], s0); s1 = fmaf(r3, W2[hb + 7], s1);
    }
    float S0 = s0 + b2[0], S1 = s1 + b2[1];
    float se = fmaxf(S0, S1) + log1pf(__expf(-fabsf(S0 - S1)));
    S[tri * BS + b] = se;   // layout (w,i,j',b) contiguous per DP step
}

// ---------------- Kernel 3: single-block inside DP, B in LDS
#define BIDX(i, j, b) ((((i) * N1) + (j)) * 9 + (b))   // stride 9 -> decorrelate banks
#define MNEG (-1e38f)

// branchless online logsumexp update (g always finite)
#define LSE_UPD(mx, s, g) { float _g = (g); float _nm = fmaxf(mx, _g); \
    s = s * __expf(mx - _nm) + __expf(_g - _nm); mx = _nm; }

__global__ __launch_bounds__(1024) void k_dp(
    const float* __restrict__ S, const int* __restrict__ lengths,
    float* __restrict__ out)
{
    __shared__ float B[N1 * N1 * 9];   // 60516 B
    const int tid = threadIdx.x;

    for (int x = tid; x < N1 * N1 * 9; x += 1024) B[x] = NEGV;
    __syncthreads();
    if (tid < N_TOK * BS) {
        int i = tid >> 3, b = tid & 7;
        B[BIDX(i, i + 1, b)] = 0.f;
    }
    __syncthreads();

    int off = 0;
    for (int w = 2; w <= N_TOK; ++w) {
        const int m  = N1 - w;
        const int nj = w - 1;
        const int cells = m * BS;
        float newB = 0.f;
        int i = 0, b = 0, k = 0;
        if (tid < cells) {
            i = tid >> 3; b = tid & 7; k = i + w;
            const float* Srow = S + (size_t)(off + i * nj) * BS + b;
            // 4 independent online-logsumexp accumulators to break the exp chain
            float mx0 = MNEG, mx1 = MNEG, mx2 = MNEG, mx3 = MNEG;
            float s0 = 0.f, s1 = 0.f, s2 = 0.f, s3 = 0.f;
            int jp = 0;
            for (; jp + 3 < nj; jp += 4) {
                float g0 = Srow[(jp + 0) * BS] + B[BIDX(i, i + 1 + jp + 0, b)] + B[BIDX(i + 1 + jp + 0, k, b)];
                float g1 = Srow[(jp + 1) * BS] + B[BIDX(i, i + 1 + jp + 1, b)] + B[BIDX(i + 1 + jp + 1, k, b)];
                float g2 = Srow[(jp + 2) * BS] + B[BIDX(i, i + 1 + jp + 2, b)] + B[BIDX(i + 1 + jp + 2, k, b)];
                float g3 = Srow[(jp + 3) * BS] + B[BIDX(i, i + 1 + jp + 3, b)] + B[BIDX(i + 1 + jp + 3, k, b)];
                LSE_UPD(mx0, s0, g0);
                LSE_UPD(mx1, s1, g1);
                LSE_UPD(mx2, s2, g2);
                LSE_UPD(mx3, s3, g3);
            }
            for (; jp < nj; ++jp) {
                float g0 = Srow[jp * BS] + B[BIDX(i, i + 1 + jp, b)] + B[BIDX(i + 1 + jp, k, b)];
                LSE_UPD(mx0, s0, g0);
            }
            float M = fmaxf(fmaxf(mx0, mx1), fmaxf(mx2, mx3));
            float ssum = s0 * __expf(mx0 - M) + s1 * __expf(mx1 - M)
                       + s2 * __expf(mx2 - M) + s3 * __expf(mx3 - M);
            newB = M + __logf(ssum);
        }
        __syncthreads();   // writes (width w) are disjoint from reads (width < w)
        if (tid < cells) B[BIDX(i, k, b)] = newB;
        off += m * nj;
        __syncthreads();
    }

    if (tid < BS) {
        int L = lengths[tid];
        out[tid] = B[BIDX(0, L, tid)];
    }
}

extern "C" void kernel_launch(void* const* d_in, const int* in_sizes, int n_in,
                              void* d_out, int out_size, void* d_ws, size_t ws_size,
                              hipStream_t stream)
{
    const float* enc = (const float*)d_in[0];
    const float* W1  = (const float*)d_in[1];
    const float* b1  = (const float*)d_in[2];
    const float* W2  = (const float*)d_in[3];
    const float* b2  = (const float*)d_in[4];
    const int* lengths = (const int*)d_in[5];

    float* ws = (float*)d_ws;
    float* P  = ws;
    float* Qb = ws + ROWF;
    float* Dd = ws + 2 * ROWF;
    float* S  = ws + 3 * ROWF;   // 85280 floats; total ws use ~1.35 MB

    k_proj<<<dim3(N1), dim3(256), 0, stream>>>(enc, W1, b1, P, Qb, Dd);
    k_score<<<dim3((NTASK + 255) / 256), dim3(256), 0, stream>>>(P, Qb, Dd, W2, b2, S);
    k_dp<<<dim3(1), dim3(1024), 0, stream>>>(S, lengths, (float*)d_out);
}

// Round 2
// 165.506 us; speedup vs baseline: 1.2215x; 1.2215x over previous
//
#include <hip/hip_runtime.h>
#include <math.h>

#define N_TOK 40
#define N1    41      // N_TOK + 1
#define BS    8
#define DD    256     // D
#define HH    256     // H
#define NTRI  10660   // C(41,3)
#define NTASK (NTRI * BS)  // 85280
#define ROWF  (BS * N1 * HH)  // 83968 floats per [b][t][h] array
#define MNEG  (-1e38f)
#define SBUF_MAX 3200   // max per-step S chunk: (41-21)*(21-1)*8 = 3200 floats

// ---------------- Kernel 1: projections P = enc@W1L, Qb = enc@W1R + b1, D = P - Q
__global__ __launch_bounds__(256) void k_proj(
    const float* __restrict__ enc, const float* __restrict__ W1,
    const float* __restrict__ b1,
    float* __restrict__ P, float* __restrict__ Qb, float* __restrict__ Dd)
{
    const int t = blockIdx.x;    // 0..40
    const int h = threadIdx.x;   // 0..255
    __shared__ float e[BS][DD];
    #pragma unroll
    for (int b = 0; b < BS; ++b)
        e[b][h] = enc[(t * BS + b) * DD + h];
    __syncthreads();

    float accP[BS], accQ[BS];
    #pragma unroll
    for (int b = 0; b < BS; ++b) { accP[b] = 0.f; accQ[b] = 0.f; }

    for (int d = 0; d < DD; ++d) {
        float wp = W1[d * HH + h];
        float wq = W1[(DD + d) * HH + h];
        #pragma unroll
        for (int b = 0; b < BS; ++b) {
            float ev = e[b][d];
            accP[b] = fmaf(ev, wp, accP[b]);
            accQ[b] = fmaf(ev, wq, accQ[b]);
        }
    }
    float bb = b1[h];
    #pragma unroll
    for (int b = 0; b < BS; ++b) {
        int idx = ((b * N1) + t) * HH + h;
        P[idx]  = accP[b];
        Qb[idx] = accQ[b] + bb;
        Dd[idx] = accP[b] - accQ[b];
    }
}

// ---------------- Kernel 2: per-triple scores SE[tri][b] = logsumexp_o(S0,S1)
__global__ __launch_bounds__(256) void k_score(
    const float* __restrict__ P, const float* __restrict__ Qb,
    const float* __restrict__ Dd, const float* __restrict__ W2,
    const float* __restrict__ b2, float* __restrict__ S)
{
    int tau = blockIdx.x * 256 + threadIdx.x;
    if (tau >= NTASK) return;
    // b-outer ordering: a wave shares b and walks consecutive triples -> P/Qb rows broadcast
    int b   = tau / NTRI;
    int tri = tau - b * NTRI;

    // decode tri -> (w, i, j') in (w,i,j') enumeration order
    int rem = tri, w = 2;
    while (true) {
        int cnt = (N1 - w) * (w - 1);
        if (rem < cnt) break;
        rem -= cnt; ++w;
    }
    int nj = w - 1;
    int i  = rem / nj;
    int jp = rem - i * nj;
    int j  = i + 1 + jp;
    int k  = i + w;

    const float4* Pr = (const float4*)(P  + ((b * N1 + i) << 8));
    const float4* Qr = (const float4*)(Qb + ((b * N1 + k) << 8));
    const float4* Dr = (const float4*)(Dd + ((b * N1 + j) << 8));

    float s0 = 0.f, s1 = 0.f;
    #pragma unroll 4
    for (int h4 = 0; h4 < HH / 4; ++h4) {
        float4 p = Pr[h4], q = Qr[h4], dd = Dr[h4];
        float r0 = fmaxf(dd.x + q.x - p.x, 0.f);
        float r1 = fmaxf(dd.y + q.y - p.y, 0.f);
        float r2 = fmaxf(dd.z + q.z - p.z, 0.f);
        float r3 = fmaxf(dd.w + q.w - p.w, 0.f);
        int hb = h4 * 8;  // W2 is [h][2] row-major; uniform index -> scalar loads
        s0 = fmaf(r0, W2[hb + 0], s0); s1 = fmaf(r0, W2[hb + 1], s1);
        s0 = fmaf(r1, W2[hb + 2], s0); s1 = fmaf(r1, W2[hb + 3], s1);
        s0 = fmaf(r2, W2[hb + 4], s0); s1 = fmaf(r2, W2[hb + 5], s1);
        s0 = fmaf(r3, W2[hb + 6], s0); s1 = fmaf(r3, W2[hb + 7], s1);
    }
    float S0 = s0 + b2[0], S1 = s1 + b2[1];
    float se = fmaxf(S0, S1) + log1pf(__expf(-fabsf(S0 - S1)));
    S[tri * BS + b] = se;   // layout (w,i,j',b) contiguous per DP step
}

// ---------------- Kernel 3: single-block inside DP
// B packed upper-triangular: cell (i,j), j>i, at tri_base(i) + (j-i-1); stride 9 over b.
__device__ __forceinline__ int tri_base(int i) { return (i * (81 - i)) >> 1; }
#define BIDX(i, j, b) ((tri_base(i) + ((j) - (i) - 1)) * 9 + (b))

// branchless online logsumexp update (g always finite)
#define LSE_UPD(mx, s, g) { float _g = (g); float _nm = fmaxf(mx, _g); \
    s = s * __expf(mx - _nm) + __expf(_g - _nm); mx = _nm; }

#define DPT 1024

__global__ __launch_bounds__(DPT) void k_dp(
    const float* __restrict__ Sg, const int* __restrict__ lengths,
    float* __restrict__ out)
{
    __shared__ float B[820 * 9];          // 29520 B, packed triangle
    __shared__ float Sbuf[2][SBUF_MAX];   // 25600 B, double-buffered S chunks
    const int tid = threadIdx.x;

    // width-1 diagonal = 0 (only entries ever read that aren't computed here)
    if (tid < N_TOK * BS) {
        int i = tid >> 3, b = tid & 7;
        B[BIDX(i, i + 1, b)] = 0.f;
    }
    // preload w=2 chunk: (N1-2)*1*BS = 312 floats
    if (tid < (N1 - 2) * BS) Sbuf[0][tid] = Sg[tid];
    __syncthreads();

    int off = 0, cur = 0;
    for (int w = 2; w <= N_TOK; ++w) {
        const int m  = N1 - w;
        const int nj = w - 1;
        const int chunk = m * nj * BS;

        // ---- issue prefetch of next chunk into registers (latency overlaps compute)
        float pf0 = 0.f, pf1 = 0.f, pf2 = 0.f, pf3 = 0.f;
        int nelems = 0;
        if (w < N_TOK) {
            nelems = (m - 1) * w * BS;           // next step's chunk size
            const float* src = Sg + off + chunk;
            if (tid              < nelems) pf0 = src[tid];
            if (tid + DPT        < nelems) pf1 = src[tid + DPT];
            if (tid + 2 * DPT    < nelems) pf2 = src[tid + 2 * DPT];
            if (tid + 3 * DPT    < nelems) pf3 = src[tid + 3 * DPT];
        }

        // ---- compute: 2 threads per (i,b) cell, contiguous-half split over j'
        const int cells = m * BS;
        if (tid < 2 * cells) {
            int c = tid >> 1, h = tid & 1;
            int i = c >> 3, b = c & 7, k = i + w;
            int nj0 = (nj + 1) >> 1;
            int lo = h ? nj0 : 0;
            int hi = h ? nj  : nj0;
            const float* Sc = &Sbuf[cur][(i * nj) * 8 + b];

            float mxA = MNEG, sA = 0.f, mxB = MNEG, sB = 0.f;
            int jp = lo;
            for (; jp + 1 < hi; jp += 2) {
                float g0 = Sc[jp * 8]
                         + B[BIDX(i, i + 1 + jp, b)]
                         + B[BIDX(i + 1 + jp, k, b)];
                float g1 = Sc[(jp + 1) * 8]
                         + B[BIDX(i, i + 2 + jp, b)]
                         + B[BIDX(i + 2 + jp, k, b)];
                LSE_UPD(mxA, sA, g0);
                LSE_UPD(mxB, sB, g1);
            }
            if (jp < hi) {
                float g0 = Sc[jp * 8]
                         + B[BIDX(i, i + 1 + jp, b)]
                         + B[BIDX(i + 1 + jp, k, b)];
                LSE_UPD(mxA, sA, g0);
            }
            // thread-level combine
            float M = fmaxf(mxA, mxB);
            float s = sA * __expf(mxA - M) + sB * __expf(mxB - M);
            // pair combine (partners are adjacent lanes, both active)
            float Mo = __shfl_xor(M, 1);
            float so = __shfl_xor(s, 1);
            float Mf = fmaxf(M, Mo);
            float sf = s * __expf(M - Mf) + so * __expf(Mo - Mf);
            if (h == 0)
                B[BIDX(i, k, b)] = Mf + __logf(sf);   // width-w entry: never read at step w
        }

        // ---- drain prefetch into the other buffer
        if (w < N_TOK) {
            float* dst = &Sbuf[cur ^ 1][0];
            if (tid              < nelems) dst[tid]            = pf0;
            if (tid + DPT        < nelems) dst[tid + DPT]      = pf1;
            if (tid + 2 * DPT    < nelems) dst[tid + 2 * DPT]  = pf2;
            if (tid + 3 * DPT    < nelems) dst[tid + 3 * DPT]  = pf3;
        }
        __syncthreads();   // single barrier per step
        cur ^= 1;
        off += chunk;
    }

    if (tid < BS) {
        int L = lengths[tid];
        out[tid] = B[BIDX(0, L, tid)];
    }
}

extern "C" void kernel_launch(void* const* d_in, const int* in_sizes, int n_in,
                              void* d_out, int out_size, void* d_ws, size_t ws_size,
                              hipStream_t stream)
{
    const float* enc = (const float*)d_in[0];
    const float* W1  = (const float*)d_in[1];
    const float* b1  = (const float*)d_in[2];
    const float* W2  = (const float*)d_in[3];
    const float* b2  = (const float*)d_in[4];
    const int* lengths = (const int*)d_in[5];

    float* ws = (float*)d_ws;
    float* P  = ws;
    float* Qb = ws + ROWF;
    float* Dd = ws + 2 * ROWF;
    float* S  = ws + 3 * ROWF;   // 85280 floats; total ws use ~1.35 MB

    k_proj<<<dim3(N1), dim3(256), 0, stream>>>(enc, W1, b1, P, Qb, Dd);
    k_score<<<dim3((NTASK + 255) / 256), dim3(256), 0, stream>>>(P, Qb, Dd, W2, b2, S);
    k_dp<<<dim3(1), dim3(DPT), 0, stream>>>(S, lengths, (float*)d_out);
}

// Round 3
// 151.877 us; speedup vs baseline: 1.3311x; 1.0897x over previous
//
#include <hip/hip_runtime.h>
#include <math.h>

#define N_TOK 40
#define N1    41      // N_TOK + 1
#define BS    8
#define DD    256     // D
#define HH    256     // H
#define NTRI  10660   // C(41,3)
#define NTASK (NTRI * BS)  // 85280
#define ROWF  (BS * N1 * HH)  // 83968 floats per [b][t][h] array
#define MNEG  (-1e38f)
#define SBUF_MAX 3200   // max per-step S chunk: (41-21)*(21-1)*8 = 3200 floats
#define DPT 1024

// ---------------- Kernel 1: projections P = enc@W1L, Qb = enc@W1R + b1, D = P - Q
__global__ __launch_bounds__(256) void k_proj(
    const float* __restrict__ enc, const float* __restrict__ W1,
    const float* __restrict__ b1,
    float* __restrict__ P, float* __restrict__ Qb, float* __restrict__ Dd)
{
    const int t = blockIdx.x;    // 0..40
    const int h = threadIdx.x;   // 0..255
    __shared__ float e[BS][DD];
    #pragma unroll
    for (int b = 0; b < BS; ++b)
        e[b][h] = enc[(t * BS + b) * DD + h];
    __syncthreads();

    float accP[BS], accQ[BS];
    #pragma unroll
    for (int b = 0; b < BS; ++b) { accP[b] = 0.f; accQ[b] = 0.f; }

    for (int d = 0; d < DD; ++d) {
        float wp = W1[d * HH + h];
        float wq = W1[(DD + d) * HH + h];
        #pragma unroll
        for (int b = 0; b < BS; ++b) {
            float ev = e[b][d];
            accP[b] = fmaf(ev, wp, accP[b]);
            accQ[b] = fmaf(ev, wq, accQ[b]);
        }
    }
    float bb = b1[h];
    #pragma unroll
    for (int b = 0; b < BS; ++b) {
        int idx = ((b * N1) + t) * HH + h;
        P[idx]  = accP[b];
        Qb[idx] = accQ[b] + bb;
        Dd[idx] = accP[b] - accQ[b];
    }
}

// ---------------- Kernel 2: per-triple scores, 16 lanes per (tri,b) task.
// Lane t covers h = t*16 .. t*16+15 -> all row reads fully coalesced
// (16 lanes x 64 B = 1 KB contiguous per float4 load instruction).
__global__ __launch_bounds__(256) void k_score(
    const float* __restrict__ P, const float* __restrict__ Qb,
    const float* __restrict__ Dd, const float* __restrict__ W2,
    const float* __restrict__ b2, float* __restrict__ S)
{
    int gt = blockIdx.x * 256 + threadIdx.x;
    int task = gt >> 4;
    int t    = gt & 15;
    if (task >= NTASK) return;
    int b   = task / NTRI;
    int tri = task - b * NTRI;

    // decode tri -> (w, i, j') in (w,i,j') enumeration order
    int rem = tri, w = 2;
    while (true) {
        int cnt = (N1 - w) * (w - 1);
        if (rem < cnt) break;
        rem -= cnt; ++w;
    }
    int nj = w - 1;
    int i  = rem / nj;
    int jp = rem - i * nj;
    int j  = i + 1 + jp;
    int k  = i + w;

    const float4* Pr  = (const float4*)(P  + ((b * N1 + i) << 8)) + t * 4;
    const float4* Qr  = (const float4*)(Qb + ((b * N1 + k) << 8)) + t * 4;
    const float4* Dr  = (const float4*)(Dd + ((b * N1 + j) << 8)) + t * 4;
    const float4* W2r = (const float4*)(W2) + t * 8;   // W2[h][2], h = t*16..t*16+15

    float s0 = 0.f, s1 = 0.f;
    #pragma unroll
    for (int q = 0; q < 4; ++q) {
        float4 p = Pr[q], qq = Qr[q], dd = Dr[q];
        float4 wa = W2r[q * 2], wb = W2r[q * 2 + 1];
        float r0 = fmaxf(dd.x + qq.x - p.x, 0.f);
        float r1 = fmaxf(dd.y + qq.y - p.y, 0.f);
        float r2 = fmaxf(dd.z + qq.z - p.z, 0.f);
        float r3 = fmaxf(dd.w + qq.w - p.w, 0.f);
        s0 = fmaf(r0, wa.x, s0); s1 = fmaf(r0, wa.y, s1);
        s0 = fmaf(r1, wa.z, s0); s1 = fmaf(r1, wa.w, s1);
        s0 = fmaf(r2, wb.x, s0); s1 = fmaf(r2, wb.y, s1);
        s0 = fmaf(r3, wb.z, s0); s1 = fmaf(r3, wb.w, s1);
    }
    #pragma unroll
    for (int d = 1; d < 16; d <<= 1) {
        s0 += __shfl_xor(s0, d);
        s1 += __shfl_xor(s1, d);
    }
    if (t == 0) {
        float S0 = s0 + b2[0], S1 = s1 + b2[1];
        S[tri * BS + b] = fmaxf(S0, S1) + log1pf(__expf(-fabsf(S0 - S1)));
    }
}

// ---------------- Kernel 3: single-block inside DP, per-width templated steps
// B packed upper-triangular: cell (i,j), j>i, at tri_base(i) + (j-i-1); stride 9 over b.
__device__ __forceinline__ int tri_base(int i) { return (i * (81 - i)) >> 1; }
#define BIDX(i, j, b) ((tri_base(i) + ((j) - (i) - 1)) * 9 + (b))

// element offset of step-W's S chunk
constexpr int soff(int W) {
    int s = 0;
    for (int v = 2; v < W; ++v) s += (N1 - v) * (v - 1);
    return s * 8;
}
// threads per cell: pow2, keep cells*T <= 1024, T <= 64, stop once T >= nj
constexpr int pick_T(int m, int nj) {
    int T = 1;
    while (2 * T <= 64 && 2 * T * m * 8 <= DPT && T < nj) T *= 2;
    return T;
}
constexpr int ilog2(int x) { int l = 0; while ((1 << l) < x) ++l; return l; }

template<int W>
__device__ __forceinline__ void dp_step(float* __restrict__ B,
                                        float (*__restrict__ Sbuf)[SBUF_MAX],
                                        const float* __restrict__ Sg, int tid)
{
    constexpr int m     = N1 - W;
    constexpr int nj    = W - 1;
    constexpr int cells = m * BS;
    constexpr int T     = pick_T(m, nj);
    constexpr int LT    = ilog2(T);
    constexpr int cur   = W & 1;          // W=2 uses buf 0 (preloaded)
    constexpr int ITER  = (nj + T - 1) / T;
    constexpr int nelems = (W < N_TOK) ? (m - 1) * W * BS : 0;

    // ---- issue prefetch of next step's chunk (L2 latency overlaps compute)
    float pf[4] = {0.f, 0.f, 0.f, 0.f};
    if constexpr (W < N_TOK) {
        const float* src = Sg + soff(W + 1);
        #pragma unroll
        for (int q = 0; q < 4; ++q)
            if (tid + q * DPT < nelems) pf[q] = src[tid + q * DPT];
    }

    // ---- compute: T threads per (i,b) cell, j' strided by T, fully unrolled
    if (tid < cells * T) {
        int c = tid >> LT;
        int h = tid & (T - 1);
        int i = c >> 3, b = c & 7, k = i + W;
        const float* Sc = &Sbuf[cur][(i * nj) * 8 + b];

        float g[ITER];
        #pragma unroll
        for (int q = 0; q < ITER; ++q) {
            int jp = h + q * T;
            bool live = (q < ITER - 1) || (jp < nj);   // compile-time true except last q
            int jj = live ? jp : 0;
            float v = Sc[jj * 8] + B[BIDX(i, i + 1 + jj, b)] + B[BIDX(i + 1 + jj, k, b)];
            g[q] = live ? v : MNEG;
        }
        // tree LSE (no serial online-update chain)
        float mx = g[0];
        #pragma unroll
        for (int q = 1; q < ITER; ++q) mx = fmaxf(mx, g[q]);
        float s = 0.f;
        #pragma unroll
        for (int q = 0; q < ITER; ++q) s += __expf(g[q] - mx);
        // NB: a lane with all-masked g has mx=MNEG; its s is annihilated by
        // exp(MNEG - real) = 0 in the butterfly below, and lane h=0 is always live.
        #pragma unroll
        for (int d = 1; d < T; d <<= 1) {
            float mo = __shfl_xor(mx, d);
            float so = __shfl_xor(s, d);
            float nm = fmaxf(mx, mo);
            s = s * __expf(mx - nm) + so * __expf(mo - nm);
            mx = nm;
        }
        if (h == 0)
            B[BIDX(i, k, b)] = mx + __logf(s);   // width-W entry: never read at step W
    }

    // ---- drain prefetch into the other buffer
    if constexpr (W < N_TOK) {
        float* dst = Sbuf[cur ^ 1];
        #pragma unroll
        for (int q = 0; q < 4; ++q)
            if (tid + q * DPT < nelems) dst[tid + q * DPT] = pf[q];
    }
    __syncthreads();   // single barrier per step
}

template<int W>
__device__ __forceinline__ void dp_from(float* __restrict__ B,
                                        float (*__restrict__ Sbuf)[SBUF_MAX],
                                        const float* __restrict__ Sg, int tid)
{
    dp_step<W>(B, Sbuf, Sg, tid);
    if constexpr (W + 1 <= N_TOK) dp_from<W + 1>(B, Sbuf, Sg, tid);
}

__global__ __launch_bounds__(DPT) void k_dp(
    const float* __restrict__ Sg, const int* __restrict__ lengths,
    float* __restrict__ out)
{
    __shared__ float B[820 * 9];          // 29520 B, packed triangle
    __shared__ float Sbuf[2][SBUF_MAX];   // 25600 B, double-buffered S chunks
    const int tid = threadIdx.x;

    // width-1 diagonal = 0 (only entries read that aren't computed here)
    if (tid < N_TOK * BS) {
        int i = tid >> 3, b = tid & 7;
        B[BIDX(i, i + 1, b)] = 0.f;
    }
    // preload w=2 chunk: (N1-2)*1*BS = 312 floats
    if (tid < (N1 - 2) * BS) Sbuf[0][tid] = Sg[tid];
    __syncthreads();

    dp_from<2>(B, Sbuf, Sg, tid);

    if (tid < BS) {
        int L = lengths[tid];
        out[tid] = B[BIDX(0, L, tid)];
    }
}

extern "C" void kernel_launch(void* const* d_in, const int* in_sizes, int n_in,
                              void* d_out, int out_size, void* d_ws, size_t ws_size,
                              hipStream_t stream)
{
    const float* enc = (const float*)d_in[0];
    const float* W1  = (const float*)d_in[1];
    const float* b1  = (const float*)d_in[2];
    const float* W2  = (const float*)d_in[3];
    const float* b2  = (const float*)d_in[4];
    const int* lengths = (const int*)d_in[5];

    float* ws = (float*)d_ws;
    float* P  = ws;
    float* Qb = ws + ROWF;
    float* Dd = ws + 2 * ROWF;
    float* S  = ws + 3 * ROWF;   // 85280 floats; total ws use ~1.35 MB

    k_proj<<<dim3(N1), dim3(256), 0, stream>>>(enc, W1, b1, P, Qb, Dd);
    k_score<<<dim3((NTASK * 16 + 255) / 256), dim3(256), 0, stream>>>(P, Qb, Dd, W2, b2, S);
    k_dp<<<dim3(1), dim3(DPT), 0, stream>>>(S, lengths, (float*)d_out);
}

// Round 4
// 143.468 us; speedup vs baseline: 1.4091x; 1.0586x over previous
//
#include <hip/hip_runtime.h>
#include <math.h>

#define N_TOK 40
#define N1    41      // N_TOK + 1
#define BS    8
#define DD    256     // D
#define HH    256     // H
#define NTRI  10660   // C(41,3)
#define NTASK (NTRI * BS)  // 85280
#define ROWF  (BS * N1 * HH)  // 83968 floats per [b][t][h] array
#define MNEG  (-1e38f)

// ---------------- Kernel 1: projections P = enc@W1L, Qb = enc@W1R + b1, D = P - Q
__global__ __launch_bounds__(256) void k_proj(
    const float* __restrict__ enc, const float* __restrict__ W1,
    const float* __restrict__ b1,
    float* __restrict__ P, float* __restrict__ Qb, float* __restrict__ Dd)
{
    const int t = blockIdx.x;    // 0..40
    const int h = threadIdx.x;   // 0..255
    __shared__ float e[BS][DD];
    #pragma unroll
    for (int b = 0; b < BS; ++b)
        e[b][h] = enc[(t * BS + b) * DD + h];
    __syncthreads();

    float accP[BS], accQ[BS];
    #pragma unroll
    for (int b = 0; b < BS; ++b) { accP[b] = 0.f; accQ[b] = 0.f; }

    for (int d = 0; d < DD; ++d) {
        float wp = W1[d * HH + h];
        float wq = W1[(DD + d) * HH + h];
        #pragma unroll
        for (int b = 0; b < BS; ++b) {
            float ev = e[b][d];
            accP[b] = fmaf(ev, wp, accP[b]);
            accQ[b] = fmaf(ev, wq, accQ[b]);
        }
    }
    float bb = b1[h];
    #pragma unroll
    for (int b = 0; b < BS; ++b) {
        int idx = ((b * N1) + t) * HH + h;
        P[idx]  = accP[b];
        Qb[idx] = accQ[b] + bb;
        Dd[idx] = accP[b] - accQ[b];
    }
}

// ---------------- Kernel 2: per-triple scores, 16 lanes per (tri,b) task.
// Lane t covers h = t*16 .. t*16+15 -> all row reads fully coalesced.
// Output layout: S[b][tri] (contiguous per-b slab for the DP blocks).
__global__ __launch_bounds__(256) void k_score(
    const float* __restrict__ P, const float* __restrict__ Qb,
    const float* __restrict__ Dd, const float* __restrict__ W2,
    const float* __restrict__ b2, float* __restrict__ S)
{
    int gt = blockIdx.x * 256 + threadIdx.x;
    int task = gt >> 4;
    int t    = gt & 15;
    if (task >= NTASK) return;
    int b   = task / NTRI;
    int tri = task - b * NTRI;

    // decode tri -> (w, i, j') in (w,i,j') enumeration order
    int rem = tri, w = 2;
    while (true) {
        int cnt = (N1 - w) * (w - 1);
        if (rem < cnt) break;
        rem -= cnt; ++w;
    }
    int nj = w - 1;
    int i  = rem / nj;
    int jp = rem - i * nj;
    int j  = i + 1 + jp;
    int k  = i + w;

    const float4* Pr  = (const float4*)(P  + ((b * N1 + i) << 8)) + t * 4;
    const float4* Qr  = (const float4*)(Qb + ((b * N1 + k) << 8)) + t * 4;
    const float4* Dr  = (const float4*)(Dd + ((b * N1 + j) << 8)) + t * 4;
    const float4* W2r = (const float4*)(W2) + t * 8;   // W2[h][2], h = t*16..t*16+15

    float s0 = 0.f, s1 = 0.f;
    #pragma unroll
    for (int q = 0; q < 4; ++q) {
        float4 p = Pr[q], qq = Qr[q], dd = Dr[q];
        float4 wa = W2r[q * 2], wb = W2r[q * 2 + 1];
        float r0 = fmaxf(dd.x + qq.x - p.x, 0.f);
        float r1 = fmaxf(dd.y + qq.y - p.y, 0.f);
        float r2 = fmaxf(dd.z + qq.z - p.z, 0.f);
        float r3 = fmaxf(dd.w + qq.w - p.w, 0.f);
        s0 = fmaf(r0, wa.x, s0); s1 = fmaf(r0, wa.y, s1);
        s0 = fmaf(r1, wa.z, s0); s1 = fmaf(r1, wa.w, s1);
        s0 = fmaf(r2, wb.x, s0); s1 = fmaf(r2, wb.y, s1);
        s0 = fmaf(r3, wb.z, s0); s1 = fmaf(r3, wb.w, s1);
    }
    #pragma unroll
    for (int d = 1; d < 16; d <<= 1) {
        s0 += __shfl_xor(s0, d);
        s1 += __shfl_xor(s1, d);
    }
    if (t == 0) {
        float S0 = s0 + b2[0], S1 = s1 + b2[1];
        S[b * NTRI + tri] = fmaxf(S0, S1) + log1pf(__expf(-fabsf(S0 - S1)));
    }
}

// ---------------- Kernel 3: per-batch single-wave DP (8 blocks x 64 threads)
// B packed upper-triangular per b: cell (i,j), j>i, at tri_base(i) + (j-i-1).
__device__ __forceinline__ int tri_base(int i) { return (i * (81 - i)) >> 1; }
#define BIDX(i, j) (tri_base(i) + ((j) - (i) - 1))

// per-b element offset of step-W's S chunk, (w,i,j') enumeration
constexpr int soff(int W) {
    int s = 0;
    for (int v = 2; v < W; ++v) s += (N1 - v) * (v - 1);
    return s;
}
// lanes per cell: pow2, cells*T <= 64, capped at 16 (reduce rounds <= 4+4)
constexpr int pick_T(int m, int nj) {
    int T = 1;
    while (T < 16 && 2 * T * m <= 64 && T < nj) T *= 2;
    return T;
}

template<int W>
__device__ __forceinline__ void dp_step(float* __restrict__ Btri,
                                        const float* __restrict__ Sl, int lane)
{
    constexpr int m  = N1 - W;
    constexpr int nj = W - 1;
    constexpr int T  = pick_T(m, nj);
    constexpr int CH = (nj + T - 1) / T;   // contiguous j' span per lane
    constexpr int base = soff(W);

    if (lane < m * T) {
        const int i  = lane / T;
        const int h  = lane % T;
        const int k  = i + W;
        const int lo = h * CH;

        float g[CH];
        #pragma unroll
        for (int q = 0; q < CH; ++q) {
            int jp = lo + q;
            bool live = (jp < nj);         // compile-time true except tail lanes
            int jj = live ? jp : 0;
            float v = Sl[base + i * nj + jj]
                    + Btri[BIDX(i, i + 1 + jj)]
                    + Btri[BIDX(i + 1 + jj, k)];
            g[q] = live ? v : MNEG;
        }
        // phase 1: max (local tree + butterfly)
        float mx = g[0];
        #pragma unroll
        for (int q = 1; q < CH; ++q) mx = fmaxf(mx, g[q]);
        #pragma unroll
        for (int d = 1; d < T; d <<= 1) mx = fmaxf(mx, __shfl_xor(mx, d));
        // phase 2: sum of exps at the final max (no rescaling chain);
        // dead evals give exp(MNEG - mx) == 0.
        float s = 0.f;
        #pragma unroll
        for (int q = 0; q < CH; ++q) s += __expf(g[q] - mx);
        #pragma unroll
        for (int d = 1; d < T; d <<= 1) s += __shfl_xor(s, d);
        if (h == 0)
            Btri[BIDX(i, k)] = mx + __logf(s);   // width-W entry: never read at step W
    }
    __syncthreads();   // single-wave workgroup: essentially free
}

template<int W>
__device__ __forceinline__ void dp_from(float* __restrict__ Btri,
                                        const float* __restrict__ Sl, int lane)
{
    dp_step<W>(Btri, Sl, lane);
    if constexpr (W + 1 <= N_TOK) dp_from<W + 1>(Btri, Sl, lane);
}

__global__ __launch_bounds__(64) void k_dp(
    const float* __restrict__ Sg, const int* __restrict__ lengths,
    float* __restrict__ out)
{
    __shared__ __align__(16) float Sl[NTRI];   // 42640 B: this b's full S
    __shared__ float Btri[820];                // 3280 B: this b's triangle
    const int lane = threadIdx.x;
    const int b    = blockIdx.x;

    // stage all of S[b] (NTRI = 2665 float4s, exact)
    const float4* src = (const float4*)(Sg + b * NTRI);
    float4* dst = (float4*)Sl;
    #pragma unroll 4
    for (int x = lane; x < NTRI / 4; x += 64) dst[x] = src[x];
    // width-1 diagonal = 0 (only read entries not computed in the loop)
    if (lane < N_TOK) Btri[tri_base(lane)] = 0.f;
    __syncthreads();

    dp_from<2>(Btri, Sl, lane);

    if (lane == 0) {
        int L = lengths[b];
        out[b] = Btri[BIDX(0, L)];
    }
}

extern "C" void kernel_launch(void* const* d_in, const int* in_sizes, int n_in,
                              void* d_out, int out_size, void* d_ws, size_t ws_size,
                              hipStream_t stream)
{
    const float* enc = (const float*)d_in[0];
    const float* W1  = (const float*)d_in[1];
    const float* b1  = (const float*)d_in[2];
    const float* W2  = (const float*)d_in[3];
    const float* b2  = (const float*)d_in[4];
    const int* lengths = (const int*)d_in[5];

    float* ws = (float*)d_ws;
    float* P  = ws;
    float* Qb = ws + ROWF;
    float* Dd = ws + 2 * ROWF;
    float* S  = ws + 3 * ROWF;   // NTASK floats; total ws use ~1.35 MB

    k_proj<<<dim3(N1), dim3(256), 0, stream>>>(enc, W1, b1, P, Qb, Dd);
    k_score<<<dim3((NTASK * 16 + 255) / 256), dim3(256), 0, stream>>>(P, Qb, Dd, W2, b2, S);
    k_dp<<<dim3(BS), dim3(64), 0, stream>>>(S, lengths, (float*)d_out);
}

// Round 5
// 143.137 us; speedup vs baseline: 1.4124x; 1.0023x over previous
//
#include <hip/hip_runtime.h>
#include <math.h>

#define N_TOK 40
#define N1    41      // N_TOK + 1
#define BS    8
#define DD    256     // D
#define HH    256     // H
#define NTRI  10660   // C(41,3)
#define NTASK (NTRI * BS)  // 85280
#define ROWF  (BS * N1 * HH)  // 83968 floats per [b][t][h] array
#define MNEG  (-1e38f)
#define DPB   256     // DP block: 4 waves

// ---------------- Kernel 1: projections P = enc@W1L, Qb = enc@W1R + b1, D = P - Q
__global__ __launch_bounds__(256) void k_proj(
    const float* __restrict__ enc, const float* __restrict__ W1,
    const float* __restrict__ b1,
    float* __restrict__ P, float* __restrict__ Qb, float* __restrict__ Dd)
{
    const int t = blockIdx.x;    // 0..40
    const int h = threadIdx.x;   // 0..255
    __shared__ float e[BS][DD];
    #pragma unroll
    for (int b = 0; b < BS; ++b)
        e[b][h] = enc[(t * BS + b) * DD + h];
    __syncthreads();

    float accP[BS], accQ[BS];
    #pragma unroll
    for (int b = 0; b < BS; ++b) { accP[b] = 0.f; accQ[b] = 0.f; }

    for (int d = 0; d < DD; ++d) {
        float wp = W1[d * HH + h];
        float wq = W1[(DD + d) * HH + h];
        #pragma unroll
        for (int b = 0; b < BS; ++b) {
            float ev = e[b][d];
            accP[b] = fmaf(ev, wp, accP[b]);
            accQ[b] = fmaf(ev, wq, accQ[b]);
        }
    }
    float bb = b1[h];
    #pragma unroll
    for (int b = 0; b < BS; ++b) {
        int idx = ((b * N1) + t) * HH + h;
        P[idx]  = accP[b];
        Qb[idx] = accQ[b] + bb;
        Dd[idx] = accP[b] - accQ[b];
    }
}

// ---------------- Kernel 2: per-triple scores, 16 lanes per (tri,b) task.
// Lane t covers h = t*16 .. t*16+15 -> all row reads fully coalesced.
// Output layout: S[b][tri] (contiguous per-b slab for the DP blocks).
__global__ __launch_bounds__(256) void k_score(
    const float* __restrict__ P, const float* __restrict__ Qb,
    const float* __restrict__ Dd, const float* __restrict__ W2,
    const float* __restrict__ b2, float* __restrict__ S)
{
    int gt = blockIdx.x * 256 + threadIdx.x;
    int task = gt >> 4;
    int t    = gt & 15;
    if (task >= NTASK) return;
    int b   = task / NTRI;
    int tri = task - b * NTRI;

    // decode tri -> (w, i, j') in (w,i,j') enumeration order
    int rem = tri, w = 2;
    while (true) {
        int cnt = (N1 - w) * (w - 1);
        if (rem < cnt) break;
        rem -= cnt; ++w;
    }
    int nj = w - 1;
    int i  = rem / nj;
    int jp = rem - i * nj;
    int j  = i + 1 + jp;
    int k  = i + w;

    const float4* Pr  = (const float4*)(P  + ((b * N1 + i) << 8)) + t * 4;
    const float4* Qr  = (const float4*)(Qb + ((b * N1 + k) << 8)) + t * 4;
    const float4* Dr  = (const float4*)(Dd + ((b * N1 + j) << 8)) + t * 4;
    const float4* W2r = (const float4*)(W2) + t * 8;   // W2[h][2], h = t*16..t*16+15

    float s0 = 0.f, s1 = 0.f;
    #pragma unroll
    for (int q = 0; q < 4; ++q) {
        float4 p = Pr[q], qq = Qr[q], dd = Dr[q];
        float4 wa = W2r[q * 2], wb = W2r[q * 2 + 1];
        float r0 = fmaxf(dd.x + qq.x - p.x, 0.f);
        float r1 = fmaxf(dd.y + qq.y - p.y, 0.f);
        float r2 = fmaxf(dd.z + qq.z - p.z, 0.f);
        float r3 = fmaxf(dd.w + qq.w - p.w, 0.f);
        s0 = fmaf(r0, wa.x, s0); s1 = fmaf(r0, wa.y, s1);
        s0 = fmaf(r1, wa.z, s0); s1 = fmaf(r1, wa.w, s1);
        s0 = fmaf(r2, wb.x, s0); s1 = fmaf(r2, wb.y, s1);
        s0 = fmaf(r3, wb.z, s0); s1 = fmaf(r3, wb.w, s1);
    }
    #pragma unroll
    for (int d = 1; d < 16; d <<= 1) {
        s0 += __shfl_xor(s0, d);
        s1 += __shfl_xor(s1, d);
    }
    if (t == 0) {
        float S0 = s0 + b2[0], S1 = s1 + b2[1];
        S[b * NTRI + tri] = fmaxf(S0, S1) + log1pf(__expf(-fabsf(S0 - S1)));
    }
}

// ---------------- Kernel 3: per-batch DP, 8 blocks x 4 waves (256 threads)
// B packed upper-triangular per b: cell (i,j), j>i, at tri_base(i) + (j-i-1).
__device__ __forceinline__ int tri_base(int i) { return (i * (81 - i)) >> 1; }
#define BIDX(i, j) (tri_base(i) + ((j) - (i) - 1))

// per-b element offset of step-W's S chunk, (w,i,j') enumeration
constexpr int soff(int W) {
    int s = 0;
    for (int v = 2; v < W; ++v) s += (N1 - v) * (v - 1);
    return s;
}
// lanes per cell: pow2, m*T <= 256, T <= 16, T < 2*nj
// -> local CH <= 4, butterfly rounds <= 4, cells never straddle a wave
constexpr int pick_T(int m, int nj) {
    int T = 1;
    while (T < 16 && m * (T * 2) <= DPB && T < nj) T *= 2;
    return T;
}

template<int W>
__device__ __forceinline__ void dp_step(float* __restrict__ Btri,
                                        const float* __restrict__ Sl, int tid)
{
    constexpr int m    = N1 - W;
    constexpr int nj   = W - 1;
    constexpr int T    = pick_T(m, nj);
    constexpr int CH   = (nj + T - 1) / T;
    constexpr int base = soff(W);

    if (tid < m * T) {
        const int i = tid / T;
        const int h = tid % T;
        const int k = i + W;

        float g[CH];
        #pragma unroll
        for (int q = 0; q < CH; ++q) {
            int jp = h + q * T;                        // strided: lanes -> consecutive addrs
            bool live = (q < CH - 1) || (jp < nj);     // compile-time true except last q
            int jj = live ? jp : 0;
            float v = Sl[base + i * nj + jj]
                    + Btri[BIDX(i, i + 1 + jj)]
                    + Btri[BIDX(i + 1 + jj, k)];
            g[q] = live ? v : MNEG;
        }
        // local tree LSE (<=4 elements)
        float mx = g[0];
        #pragma unroll
        for (int q = 1; q < CH; ++q) mx = fmaxf(mx, g[q]);
        float s = 0.f;
        #pragma unroll
        for (int q = 0; q < CH; ++q) s += __expf(g[q] - mx);
        // in-wave fused online-LSE butterfly over T lanes (<=4 rounds).
        // Fully-dead lanes (mx==MNEG) are annihilated: exp(MNEG - real) == 0,
        // and lane h==0 is always live.
        #pragma unroll
        for (int d = 1; d < T; d <<= 1) {
            float mo = __shfl_xor(mx, d);
            float so = __shfl_xor(s, d);
            float nm = fmaxf(mx, mo);
            s = s * __expf(mx - nm) + so * __expf(mo - nm);
            mx = nm;
        }
        if (h == 0)
            Btri[BIDX(i, k)] = mx + __logf(s);   // width-W entry: never read at step W
    }
    __syncthreads();   // one 4-wave barrier per step
}

template<int W>
__device__ __forceinline__ void dp_from(float* __restrict__ Btri,
                                        const float* __restrict__ Sl, int tid)
{
    dp_step<W>(Btri, Sl, tid);
    if constexpr (W + 1 <= N_TOK) dp_from<W + 1>(Btri, Sl, tid);
}

__global__ __launch_bounds__(DPB) void k_dp(
    const float* __restrict__ Sg, const int* __restrict__ lengths,
    float* __restrict__ out)
{
    __shared__ __align__(16) float Sl[NTRI];   // 42640 B: this b's full S
    __shared__ float Btri[820];                // 3280 B: this b's triangle
    const int tid = threadIdx.x;
    const int b   = blockIdx.x;

    // stage all of S[b]: NTRI/4 = 2665 float4s (exact), 16B-aligned per b
    const float4* src = (const float4*)(Sg + b * NTRI);
    float4* dst = (float4*)Sl;
    for (int x = tid; x < NTRI / 4; x += DPB) dst[x] = src[x];
    // width-1 diagonal = 0 (only read entries not computed in the loop)
    if (tid < N_TOK) Btri[tri_base(tid)] = 0.f;
    __syncthreads();

    dp_from<2>(Btri, Sl, tid);

    if (tid == 0) {
        int L = lengths[b];
        out[b] = Btri[BIDX(0, L)];
    }
}

extern "C" void kernel_launch(void* const* d_in, const int* in_sizes, int n_in,
                              void* d_out, int out_size, void* d_ws, size_t ws_size,
                              hipStream_t stream)
{
    const float* enc = (const float*)d_in[0];
    const float* W1  = (const float*)d_in[1];
    const float* b1  = (const float*)d_in[2];
    const float* W2  = (const float*)d_in[3];
    const float* b2  = (const float*)d_in[4];
    const int* lengths = (const int*)d_in[5];

    float* ws = (float*)d_ws;
    float* P  = ws;
    float* Qb = ws + ROWF;
    float* Dd = ws + 2 * ROWF;
    float* S  = ws + 3 * ROWF;   // NTASK floats; total ws use ~1.35 MB

    k_proj<<<dim3(N1), dim3(256), 0, stream>>>(enc, W1, b1, P, Qb, Dd);
    k_score<<<dim3((NTASK * 16 + 255) / 256), dim3(256), 0, stream>>>(P, Qb, Dd, W2, b2, S);
    k_dp<<<dim3(BS), dim3(DPB), 0, stream>>>(S, lengths, (float*)d_out);
}